// Round 1
// 82.360 us; speedup vs baseline: 1.0726x; 1.0726x over previous
//
#include <hip/hip_runtime.h>
#include <math.h>

// Problem constants
#define Nn   8192
#define DXc  64
#define DZc  128
#define DYc  16
#define Hc   512
#define NKC  21     // k-chunks of 32 in concat K: 16 (S=512) + 4 (z=128) + 1 (y=16+pad)

typedef short bf16x8 __attribute__((ext_vector_type(8)));   // 8 bf16 = 4 VGPRs
typedef short bf16x4 __attribute__((ext_vector_type(4)));   // 4 bf16 = 2 VGPRs
typedef float f32x4  __attribute__((ext_vector_type(4)));

__device__ __forceinline__ float fast_tanh(float x) {
    float e = __expf(2.0f * x);             // exact limits at +/-inf, ~1e-7 rel err
    return 1.0f - 2.0f / (e + 1.0f);
}
__device__ __forceinline__ short f2bf(float f) {            // fp32 -> bf16 RNE
    unsigned u = __float_as_uint(f);
    return (short)((u + 0x7FFFu + ((u >> 16) & 1u)) >> 16);
}
__device__ __forceinline__ bf16x8 pack8(float4 a, float4 b) {
    bf16x8 r;
    r[0]=f2bf(a.x); r[1]=f2bf(a.y); r[2]=f2bf(a.z); r[3]=f2bf(a.w);
    r[4]=f2bf(b.x); r[5]=f2bf(b.y); r[6]=f2bf(b.z); r[7]=f2bf(b.w);
    return r;
}

// ===================== prep: flat, one bf16x8 chunk per thread (58 blocks) =====================
// Fragment block = 1 KB: 64 lanes x 16 B.
// Wb chunk c in [0,4096): block=c>>6 (= jt*2+kc2); element i = W1[k][j],
//   j=(block>>1)*16+(lane&15), k=(block&1)*32+(lane>>4)*8+i
// Wf chunk c2 in [0,10752): block = zt*21+kc; z=(block/21)*16+(lane&15),
//   k=(block%21)*32+(lane>>4)*8+i over concat K=[W2 | -A^T | -B^T | 0]
__global__ __launch_bounds__(256)
void prep_kernel(const float* __restrict__ W1,
                 const float* __restrict__ W2,
                 const float* __restrict__ A,
                 const float* __restrict__ Bm,
                 short* __restrict__ Wb,
                 short* __restrict__ Wf,
                 float* __restrict__ out) {
    int c = blockIdx.x * 256 + threadIdx.x;
    if (c == 0) out[0] = 0.f;

    if (c < 4096) {                       // ---- W1 -> Wb ----
        int lane = c & 63, block = c >> 6;
        int n16 = lane & 15, q = lane >> 4;
        int j = (block >> 1) * 16 + n16;
        int k0 = (block & 1) * 32 + q * 8;
        bf16x8 v;
#pragma unroll
        for (int i = 0; i < 8; i++) v[i] = f2bf(W1[(size_t)(k0 + i) * Hc + j]);
        *(bf16x8*)(Wb + (size_t)c * 8) = v;
    } else {                              // ---- [W2; -A^T; -B^T; 0] -> Wf ----
        int c2 = c - 4096;                // < 10752
        int lane = c2 & 63, block = c2 >> 6;          // block < 168
        int zt = block / 21, kc = block % 21;
        int n16 = lane & 15, q = lane >> 4;
        int z = zt * 16 + n16;
        bf16x8 v = (bf16x8){0,0,0,0,0,0,0,0};
        if (kc < 16) {
            int k0 = kc * 32 + q * 8;
#pragma unroll
            for (int i = 0; i < 8; i++) v[i] = f2bf(W2[(size_t)(k0 + i) * DZc + z]);
        } else if (kc < 20) {
            int c0 = (kc - 16) * 32 + q * 8;
            float4 a0 = *(const float4*)(A + (size_t)z * DZc + c0);
            float4 a1 = *(const float4*)(A + (size_t)z * DZc + c0 + 4);
            v[0]=f2bf(-a0.x); v[1]=f2bf(-a0.y); v[2]=f2bf(-a0.z); v[3]=f2bf(-a0.w);
            v[4]=f2bf(-a1.x); v[5]=f2bf(-a1.y); v[6]=f2bf(-a1.z); v[7]=f2bf(-a1.w);
        } else if (q < 2) {
            float4 b0 = *(const float4*)(Bm + (size_t)z * DYc + q * 8);
            float4 b1 = *(const float4*)(Bm + (size_t)z * DYc + q * 8 + 4);
            v[0]=f2bf(-b0.x); v[1]=f2bf(-b0.y); v[2]=f2bf(-b0.z); v[3]=f2bf(-b0.w);
            v[4]=f2bf(-b1.x); v[5]=f2bf(-b1.y); v[6]=f2bf(-b1.z); v[7]=f2bf(-b1.w);
        }
        *(bf16x8*)(Wf + (size_t)c2 * 8) = v;
    }
}

#define MFMA16(a, b, c) __builtin_amdgcn_mfma_f32_16x16x32_bf16((a), (b), (c), 0, 0, 0)

// ===================== main: 32 samples/block, 512 threads (8 waves), 256 blocks =====================
// Phase A: ALL input->bf16 fragment conversion done ONCE cooperatively into LDS
//   (previously every one of the 8 waves redundantly converted the same x/tanh(x)/z/y).
// Phase B: swapped MFMA operands (A=W1 frag, B=x frag) => C row = j, col = sample,
//   so each thread's 4 s-values are 4 consecutive j => single contiguous ds_write_b64.
// Phase C / corrections / epilogue: unchanged math, A-frags now ds_read_b128 from LDS.
__global__ __launch_bounds__(512, 2)
void pde_main(const float* __restrict__ z_pred,
              const float* __restrict__ x_label,
              const float* __restrict__ y_label,
              const float* __restrict__ b1,
              const short* __restrict__ Wb,
              const short* __restrict__ Wf,
              float* __restrict__ out) {
    __shared__ __align__(16) short sS[2][16 * 512];  // 32 KB, fragment-major S tiles
    __shared__ __align__(16) short xf[2][2 * 512];   // 4 KB  x  bf16 frags [g][kc*512+lane*8+e]
    __shared__ __align__(16) short tf[2][2 * 512];   // 4 KB  tanh(x) frags
    __shared__ __align__(16) short zf[2][4 * 512];   // 8 KB  z_pred frags
    __shared__ __align__(16) short yf[2][512];       // 2 KB  y frags (q>=2 zero-padded)
    __shared__ float red[8][2][16];

    const int tid  = threadIdx.x;
    const int w    = tid >> 6;
    const int lane = tid & 63;
    const int n16  = lane & 15;
    const int q    = lane >> 4;
    const int n0   = blockIdx.x * 32;

    // ---------------- phase A: cooperative convert-to-LDS ----------------
    {
        const int s  = tid >> 4;          // sample 0..31
        const int g  = s >> 4;
        const int ns = s & 15;

        // x + tanh(x): each thread owns 4 consecutive x values (coalesced float4)
        {
            const int kc4 = tid & 15;     // 4-float chunk, k0 = kc4*4
            float4 v = *(const float4*)(x_label + (size_t)n0 * DXc + (size_t)tid * 4);
            const int off = (kc4 >> 3) * 512 + (ns + ((kc4 >> 1) & 3) * 16) * 8 + (kc4 & 1) * 4;
            bf16x4 xs, ts;
            xs[0]=f2bf(v.x); xs[1]=f2bf(v.y); xs[2]=f2bf(v.z); xs[3]=f2bf(v.w);
            ts[0]=f2bf(fast_tanh(v.x)); ts[1]=f2bf(fast_tanh(v.y));
            ts[2]=f2bf(fast_tanh(v.z)); ts[3]=f2bf(fast_tanh(v.w));
            *(bf16x4*)&xf[g][off] = xs;
            *(bf16x4*)&tf[g][off] = ts;
        }

        // z_pred: each thread owns 8 consecutive values (coalesced 2x float4)
        {
            const int kc8 = tid & 15;     // 8-float chunk, k0 = kc8*8
            const float* zp = z_pred + (size_t)n0 * DZc + (size_t)tid * 8;
            bf16x8 zv = pack8(*(const float4*)zp, *(const float4*)(zp + 4));
            *(bf16x8*)&zf[g][(kc8 >> 2) * 512 + (ns + (kc8 & 3) * 16) * 8] = zv;
        }

        // y_label (threads 0..63) + zero-pad of the q>=2 half (threads 64..127)
        if (tid < 64) {
            const int sy = tid >> 1, ky = tid & 1;
            const float* yp = y_label + (size_t)(n0 + sy) * DYc + ky * 8;
            bf16x8 yv = pack8(*(const float4*)yp, *(const float4*)(yp + 4));
            *(bf16x8*)&yf[sy >> 4][((sy & 15) + ky * 16) * 8] = yv;
        } else if (tid < 128) {
            const int t2 = tid - 64;
            const int sy = t2 >> 1, qy = 2 + (t2 & 1);
            *(bf16x8*)&yf[sy >> 4][((sy & 15) + qy * 16) * 8] = (bf16x8){0,0,0,0,0,0,0,0};
        }
    }
    __syncthreads();

    // ---- pull x / tanh(x) B-fragments into registers (ds_read_b128, conflict-free) ----
    bf16x8 bx[2][2], bt[2][2];
#pragma unroll
    for (int g = 0; g < 2; g++)
#pragma unroll
        for (int kc = 0; kc < 2; kc++) {
            bx[g][kc] = *(const bf16x8*)&xf[g][kc * 512 + lane * 8];
            bt[g][kc] = *(const bf16x8*)&tf[g][kc * 512 + lane * 8];
        }

    // ---------------- phase B: 4 j-tiles per wave, operands swapped ----------------
#pragma unroll
    for (int t = 0; t < 4; t++) {
        const int jt = 4 * w + t;
        const short* apw = Wb + (size_t)(jt * 2 * 64 + lane) * 8;
        bf16x8 aw0 = *(const bf16x8*)apw;
        bf16x8 aw1 = *(const bf16x8*)(apw + 512);                 // kc2=1 block
        f32x4 bj = *(const f32x4*)(b1 + jt * 16 + q * 4);         // C row = q*4+r -> j
        // s-store: j = jt*16 + q*4 + r, sample = n16; frag addr for phase C reads
        const int soff = (jt >> 1) * 512
                       + (n16 + ((((jt & 1) << 1) | (q >> 1)) * 16)) * 8
                       + (q & 1) * 4;
#pragma unroll
        for (int g = 0; g < 2; g++) {
            f32x4 h = (f32x4){0.f,0.f,0.f,0.f};
            f32x4 u = (f32x4){0.f,0.f,0.f,0.f};
            h = MFMA16(aw0, bx[g][0], h);  h = MFMA16(aw1, bx[g][1], h);
            u = MFMA16(aw0, bt[g][0], u);  u = MFMA16(aw1, bt[g][1], u);
            bf16x4 sv;
#pragma unroll
            for (int r = 0; r < 4; r++) {
                float tv = fast_tanh(h[r] + bj[r]);
                sv[r] = f2bf((1.f - tv * tv) * u[r]);
            }
            *(bf16x4*)&sS[g][soff] = sv;                          // one ds_write_b64
        }
    }

    // ---- corrections (pre-barrier; overlap other waves' phase B): z-tile w ----
    const short* wfb = Wf + (size_t)(w * NKC * 64 + lane) * 8;    // kc stride = 512 bf16
    f32x4 acc[2] = {(f32x4){0.f,0.f,0.f,0.f}, (f32x4){0.f,0.f,0.f,0.f}};
    {
#pragma unroll
        for (int kcl = 0; kcl < 4; kcl++) {
            bf16x8 bz = *(const bf16x8*)(wfb + (16 + kcl) * 512);
#pragma unroll
            for (int g = 0; g < 2; g++) {
                bf16x8 az = *(const bf16x8*)&zf[g][kcl * 512 + lane * 8];
                acc[g] = MFMA16(az, bz, acc[g]);
            }
        }
        bf16x8 by = *(const bf16x8*)(wfb + 20 * 512);
#pragma unroll
        for (int g = 0; g < 2; g++) {
            bf16x8 ay = *(const bf16x8*)&yf[g][lane * 8];         // q>=2 lanes read zeros
            acc[g] = MFMA16(ay, by, acc[g]);
        }
    }

    __syncthreads();

    // ---- phase C: S @ Wc over K=512; weight frag loaded once, used for both groups ----
#pragma unroll
    for (int kc = 0; kc < 16; kc++) {
        bf16x8 bk = *(const bf16x8*)(wfb + kc * 512);
        bf16x8 sa0 = *(const bf16x8*)&sS[0][kc * 512 + lane * 8];
        bf16x8 sa1 = *(const bf16x8*)&sS[1][kc * 512 + lane * 8];
        acc[0] = MFMA16(sa0, bk, acc[0]);
        acc[1] = MFMA16(sa1, bk, acc[1]);
    }

    // ---- epilogue: per-sample sum of squares over this wave's 16 z, cross-wave reduce ----
#pragma unroll
    for (int g = 0; g < 2; g++) {
#pragma unroll
        for (int reg = 0; reg < 4; reg++) {
            float sq = acc[g][reg] * acc[g][reg];
            sq += __shfl_xor(sq, 1);
            sq += __shfl_xor(sq, 2);
            sq += __shfl_xor(sq, 4);
            sq += __shfl_xor(sq, 8);
            if (n16 == 0) red[w][g][q * 4 + reg] = sq;
        }
    }
    __syncthreads();

    if (tid < 32) {
        const int g = tid >> 4, r = tid & 15;
        float tot = 0.f;
#pragma unroll
        for (int i = 0; i < 8; i++) tot += red[i][g][r];
        float nrm = sqrtf(tot);
        nrm += __shfl_xor(nrm, 1);
        nrm += __shfl_xor(nrm, 2);
        nrm += __shfl_xor(nrm, 4);
        nrm += __shfl_xor(nrm, 8);
        nrm += __shfl_xor(nrm, 16);
        if (tid == 0) atomicAdd(out, nrm * (1.0f / (float)Nn));
    }
}

extern "C" void kernel_launch(void* const* d_in, const int* in_sizes, int n_in,
                              void* d_out, int out_size, void* d_ws, size_t ws_size,
                              hipStream_t stream) {
    const float* z_pred  = (const float*)d_in[0];
    const float* x_label = (const float*)d_in[1];
    const float* y_label = (const float*)d_in[2];
    const float* W1      = (const float*)d_in[3];
    const float* b1      = (const float*)d_in[4];
    const float* W2      = (const float*)d_in[5];
    // d_in[6] = b2: cancels in the Jacobian-vector product
    const float* A       = (const float*)d_in[7];
    const float* Bm      = (const float*)d_in[8];

    short* Wb = (short*)d_ws;                    // 64 KB fragment-major W1
    short* Wf = Wb + 512 * DXc;                  // 168 KB fragment-major [W2; -A^T; -B^T]

    prep_kernel<<<58, 256, 0, stream>>>(W1, W2, A, Bm, Wb, Wf, (float*)d_out);
    pde_main<<<Nn / 32, 512, 0, stream>>>(z_pred, x_label, y_label, b1, Wb, Wf, (float*)d_out);
}